// Round 1
// baseline (275.835 us; speedup 1.0000x reference)
//
#include <hip/hip_runtime.h>
#include <math.h>

// Problem constants (from reference): B=8, C=512, L=4096, fp32.
#define C_CH   512
#define TOPK   256   // C * (1 - EXCHANGE_RATIO)
#define B_N    8
#define L_LEN  4096
#define L4     (L_LEN / 4)        // 1024 float4 per channel row
#define NVEC   (B_N * C_CH * L4)  // 4,194,304 float4 per output tensor

// Build per-output-channel source maps.
// map1[c]: source for y1 channel c. Value s: s <  C_CH -> x1 channel s
//                                            s >= C_CH -> x2 channel (s - C_CH)
// map2[c]: source for y2 channel c. Value s: s <  C_CH -> x2 channel s
//                                            s >= C_CH -> x1 channel (s - C_CH)
// Semantics: channel c is "top" iff rank of |bn[c]| < TOPK, rank ties broken by
// lower index first (matches jax.lax.top_k). Non-top channels of y1 take x2's
// non-top channels, aligned by ascending-index position (and vice versa).
__global__ void build_maps(const float* __restrict__ bn1,
                           const float* __restrict__ bn2,
                           int* __restrict__ map1,
                           int* __restrict__ map2) {
    __shared__ float a1[C_CH], a2[C_CH];
    __shared__ int istop1[C_CH], istop2[C_CH];
    __shared__ int nontop1[C_CH], nontop2[C_CH];  // first (C_CH-TOPK) entries used
    const int t = threadIdx.x;  // blockDim.x == C_CH
    a1[t] = fabsf(bn1[t]);
    a2[t] = fabsf(bn2[t]);
    __syncthreads();

    const float v1 = a1[t], v2 = a2[t];
    int r1 = 0, r2 = 0;
    for (int j = 0; j < C_CH; ++j) {
        const float b1 = a1[j], b2 = a2[j];
        r1 += (b1 > v1) || (b1 == v1 && j < t);
        r2 += (b2 > v2) || (b2 == v2 && j < t);
    }
    const int top1 = (r1 < TOPK);
    const int top2 = (r2 < TOPK);
    istop1[t] = top1;
    istop2[t] = top2;
    __syncthreads();

    // Position of this channel among non-top channels (ascending index order).
    int p1 = -1, p2 = -1;
    if (!top1) {
        int p = 0;
        for (int j = 0; j < t; ++j) p += !istop1[j];
        p1 = p;
        nontop1[p] = t;
    }
    if (!top2) {
        int p = 0;
        for (int j = 0; j < t; ++j) p += !istop2[j];
        p2 = p;
        nontop2[p] = t;
    }
    __syncthreads();

    map1[t] = top1 ? t : (C_CH + nontop2[p1]);
    map2[t] = top2 ? t : (C_CH + nontop1[p2]);
}

// Vectorized gather-copy: one float4 per thread per output.
__global__ __launch_bounds__(256) void exchange_copy(
        const float4* __restrict__ x1,
        const float4* __restrict__ x2,
        const int* __restrict__ map1,
        const int* __restrict__ map2,
        float4* __restrict__ y1,
        float4* __restrict__ y2) {
    const int idx = blockIdx.x * blockDim.x + threadIdx.x;  // [0, NVEC)
    const int off = idx & (L4 - 1);
    const int row = idx >> 10;          // b*C + c
    const int c   = row & (C_CH - 1);
    const int b   = row >> 9;

    const int m1 = map1[c];
    const int m2 = map2[c];

    const float4* s1 = (m1 < C_CH) ? x1 : x2;
    const float4* s2 = (m2 < C_CH) ? x2 : x1;
    const int c1 = m1 & (C_CH - 1);
    const int c2 = m2 & (C_CH - 1);

    const int base_b = b << 9;  // b * C
    y1[idx] = s1[(((base_b | c1) << 10) | off)];
    y2[idx] = s2[(((base_b | c2) << 10) | off)];
}

extern "C" void kernel_launch(void* const* d_in, const int* in_sizes, int n_in,
                              void* d_out, int out_size, void* d_ws, size_t ws_size,
                              hipStream_t stream) {
    const float* x1  = (const float*)d_in[0];
    const float* x2  = (const float*)d_in[1];
    const float* bn1 = (const float*)d_in[2];
    const float* bn2 = (const float*)d_in[3];

    float* y1 = (float*)d_out;                       // first B*C*L floats
    float* y2 = (float*)d_out + (B_N * C_CH * L_LEN);  // second output

    int* map1 = (int*)d_ws;
    int* map2 = map1 + C_CH;

    build_maps<<<1, C_CH, 0, stream>>>(bn1, bn2, map1, map2);

    const int threads = 256;
    const int blocks = NVEC / threads;  // 16384
    exchange_copy<<<blocks, threads, 0, stream>>>(
        (const float4*)x1, (const float4*)x2, map1, map2,
        (float4*)y1, (float4*)y2);
}

// Round 2
// 265.452 us; speedup vs baseline: 1.0391x; 1.0391x over previous
//
#include <hip/hip_runtime.h>
#include <math.h>

// Problem constants (from reference): B=8, C=512, L=4096, fp32.
#define C_CH   512
#define TOPK   256   // C * (1 - EXCHANGE_RATIO)
#define B_N    8
#define L_LEN  4096
#define L4     (L_LEN / 4)        // 1024 float4 per channel row
#define ROWS   (B_N * C_CH)       // 4096 (b,c) rows per tensor

// Build per-output-channel source maps.
// map1[c]: source for y1 channel c. s < C_CH -> x1 channel s; else x2 channel s-C_CH.
// map2[c]: source for y2 channel c. s < C_CH -> x2 channel s; else x1 channel s-C_CH.
// Channel c is "top" iff rank of |bn[c]| < TOPK (ties -> lower index first, matching
// jax.lax.top_k). Non-top channels are exchanged, aligned by ascending-index position.
__global__ __launch_bounds__(C_CH) void build_maps(
        const float* __restrict__ bn1,
        const float* __restrict__ bn2,
        int* __restrict__ map1,
        int* __restrict__ map2) {
    __shared__ float2 a12[C_CH];
    __shared__ int nt1[C_CH - TOPK], nt2[C_CH - TOPK];
    __shared__ int wsum1[8], wsum2[8];
    const int t = threadIdx.x;
    const float v1 = fabsf(bn1[t]);
    const float v2 = fabsf(bn2[t]);
    a12[t] = make_float2(v1, v2);
    __syncthreads();

    // Rank among |bn| values (descending, ties by lower index).
    int r1 = 0, r2 = 0;
#pragma unroll 8
    for (int j = 0; j < C_CH; ++j) {
        const float2 bj = a12[j];
        r1 += (bj.x > v1) || (bj.x == v1 && j < t);
        r2 += (bj.y > v2) || (bj.y == v2 && j < t);
    }
    const bool non1 = (r1 >= TOPK);
    const bool non2 = (r2 >= TOPK);

    // Ballot-based prefix count of non-top flags (position in ascending index order).
    const unsigned long long m1 = __ballot(non1);
    const unsigned long long m2 = __ballot(non2);
    const int lane = t & 63, w = t >> 6;
    const unsigned long long below = (1ULL << lane) - 1ULL;
    const int lp1 = __popcll(m1 & below);
    const int lp2 = __popcll(m2 & below);
    if (lane == 0) { wsum1[w] = __popcll(m1); wsum2[w] = __popcll(m2); }
    __syncthreads();
    int base1 = 0, base2 = 0;
#pragma unroll
    for (int i = 0; i < 8; ++i) {
        base1 += (i < w) ? wsum1[i] : 0;
        base2 += (i < w) ? wsum2[i] : 0;
    }
    const int p1 = base1 + lp1;
    const int p2 = base2 + lp2;
    if (non1) nt1[p1] = t;
    if (non2) nt2[p2] = t;
    __syncthreads();

    map1[t] = non1 ? (C_CH + nt2[p1]) : t;
    map2[t] = non2 ? (C_CH + nt1[p2]) : t;
}

// One block per (b, c) output row; 256 threads x 4 float4 each (1024 float4 = 16 KB
// per tensor row). Channel index is block-uniform -> map loads are scalar, data
// addresses are SGPR-base + lane offset. All 8 loads issued before any store (MLP).
__global__ __launch_bounds__(256) void exchange_copy(
        const float4* __restrict__ x1,
        const float4* __restrict__ x2,
        const int* __restrict__ map1,
        const int* __restrict__ map2,
        float4* __restrict__ y1,
        float4* __restrict__ y2) {
    const int row = blockIdx.x;       // b*C + c
    const int c = row & (C_CH - 1);
    const int b = row >> 9;

    const int m1 = map1[c];           // uniform -> s_load
    const int m2 = map2[c];
    const float4* __restrict__ s1 = (m1 < C_CH) ? x1 : x2;
    const float4* __restrict__ s2 = (m2 < C_CH) ? x2 : x1;
    const size_t src1 = (size_t)((b << 9) | (m1 & (C_CH - 1))) << 10;
    const size_t src2 = (size_t)((b << 9) | (m2 & (C_CH - 1))) << 10;
    const size_t dst  = (size_t)row << 10;

    const float4* __restrict__ p1 = s1 + src1;
    const float4* __restrict__ p2 = s2 + src2;
    float4* __restrict__ q1 = y1 + dst;
    float4* __restrict__ q2 = y2 + dst;

    const int t = threadIdx.x;
    float4 r[4], s[4];
#pragma unroll
    for (int k = 0; k < 4; ++k) r[k] = p1[t + 256 * k];
#pragma unroll
    for (int k = 0; k < 4; ++k) s[k] = p2[t + 256 * k];
#pragma unroll
    for (int k = 0; k < 4; ++k) q1[t + 256 * k] = r[k];
#pragma unroll
    for (int k = 0; k < 4; ++k) q2[t + 256 * k] = s[k];
}

extern "C" void kernel_launch(void* const* d_in, const int* in_sizes, int n_in,
                              void* d_out, int out_size, void* d_ws, size_t ws_size,
                              hipStream_t stream) {
    const float* x1  = (const float*)d_in[0];
    const float* x2  = (const float*)d_in[1];
    const float* bn1 = (const float*)d_in[2];
    const float* bn2 = (const float*)d_in[3];

    float* y1 = (float*)d_out;                         // first B*C*L floats
    float* y2 = (float*)d_out + (B_N * C_CH * L_LEN);  // second output

    int* map1 = (int*)d_ws;
    int* map2 = map1 + C_CH;

    build_maps<<<1, C_CH, 0, stream>>>(bn1, bn2, map1, map2);

    exchange_copy<<<ROWS, 256, 0, stream>>>(
        (const float4*)x1, (const float4*)x2, map1, map2,
        (float4*)y1, (float4*)y2);
}